// Round 9
// baseline (116.399 us; speedup 1.0000x reference)
//
#include <hip/hip_runtime.h>

typedef __attribute__((ext_vector_type(8))) short bf16x8;
typedef __attribute__((ext_vector_type(4))) float f32x4;
typedef __attribute__((ext_vector_type(16))) float f32x16;
typedef __attribute__((ext_vector_type(4))) unsigned short us4;

__device__ __forceinline__ unsigned short f2bf(float f) {
    unsigned int u = __builtin_bit_cast(unsigned int, f);
    u = (u + 0x7FFFu + ((u >> 16) & 1u)) >> 16;
    return (unsigned short)u;
}
__device__ __forceinline__ float bf2f(unsigned short h) {
    return __builtin_bit_cast(float, (unsigned int)h << 16);
}

// ---------------- fold BN into weights, emit bf16 ----------------
__global__ __launch_bounds__(256) void fold_weights_k(
    const float* __restrict__ Wq, const float* __restrict__ sq, const float* __restrict__ bq,
    const float* __restrict__ Wk, const float* __restrict__ sk, const float* __restrict__ bk,
    const float* __restrict__ Wv, const float* __restrict__ sv, const float* __restrict__ bv,
    const float* __restrict__ Wp, const float* __restrict__ sp,
    unsigned short* __restrict__ Wqkv, unsigned short* __restrict__ Wpf, float* __restrict__ bqkv)
{
    int i = blockIdx.x * 256 + threadIdx.x;
    if (i < 393216) {                       // Wqkv [1024][384]
        int o = i / 384;
        float w, s;
        if (o < 256)      { w = Wq[i];                s = sq[o]; }
        else if (o < 512) { w = Wk[i - 256 * 384];    s = sk[o - 256]; }
        else              { w = Wv[i - 512 * 384];    s = sv[o - 512]; }
        Wqkv[i] = f2bf(w * s);
    } else if (i < 589824) {                // Wpf [384][512]
        int j = i - 393216;
        Wpf[j] = f2bf(Wp[j] * sp[j >> 9]);
    } else if (i < 590848) {
        int o = i - 589824;
        bqkv[o] = (o < 256) ? bq[o] : (o < 512 ? bk[o - 256] : bv[o - 512]);
    }
}

// ---------------- x [b][384][4096] f32 -> xT [b][4096][384] bf16 (vectorized) ----------------
__global__ __launch_bounds__(256) void transpose_x_k(const float* __restrict__ x,
                                                     unsigned short* __restrict__ xT)
{
    __shared__ unsigned short t[64][72];
    const int b = blockIdx.z, cb = blockIdx.y << 6, nb = blockIdx.x << 6;
    const int tid = threadIdx.x;
    const float* xb = x + ((long)b * 384 + cb) * 4096 + nb;
    const int n4 = (tid & 15) * 4;
    #pragma unroll
    for (int p = 0; p < 4; ++p) {
        int c = (tid >> 4) + p * 16;
        float4 v = *reinterpret_cast<const float4*>(xb + (long)c * 4096 + n4);
        us4 o = { f2bf(v.x), f2bf(v.y), f2bf(v.z), f2bf(v.w) };
        *reinterpret_cast<us4*>(&t[c][n4]) = o;
    }
    __syncthreads();
    const int c4 = (tid & 15) * 4;
    unsigned short* ob = xT + ((long)b * 4096 + nb) * 384 + cb;
    #pragma unroll
    for (int p = 0; p < 4; ++p) {
        int n = (tid >> 4) + p * 16;
        us4 o = { t[c4][n], t[c4 + 1][n], t[c4 + 2][n], t[c4 + 3][n] };
        *reinterpret_cast<us4*>(ob + (long)n * 384 + c4) = o;
    }
}

// ---------------- QKV GEMM: 128x128 tile, BK=32, 32x32x16 MFMA, 3-buf depth-2 ----------------
// Same LDS byte layout / staging map as R8 (conflict-free, row-pair-packed 128B rows);
// only the read indexing and MFMA shape change: 96 MFMAs/wave instead of 192,
// 8 ds_reads/tile instead of 16.
__global__ __launch_bounds__(256, 3) void gemm_qkv_k(
    const unsigned short* __restrict__ A,     // Wqkv [1024][384]
    const unsigned short* __restrict__ Bt,    // xT   [b][4096][384]
    const float* __restrict__ bias,
    unsigned short* __restrict__ q_out,
    unsigned short* __restrict__ kv_out)
{
    __shared__ unsigned short As[3 * 4096];   // 3 x 128 rows x 32 k (8 KB)
    __shared__ unsigned short Bs[3 * 4096];
    const int tid = threadIdx.x;
    const int lane = tid & 63;
    const int w = tid >> 6, wr = w >> 1, wc = w & 1;
    const int col = lane & 31, khalf = lane >> 5;
    const int b = blockIdx.z;
    const int n0 = blockIdx.x * 128, m0 = blockIdx.y * 128;
    const unsigned short* Bb = Bt + (long)b * 4096 * 384;

    // staging granule map (inverse of read swizzle): granule i -> (row, k-slice)
    const int i0 = tid, i1 = tid + 256;
    const int p0 = i0 >> 3, v0 = (i0 & 7) ^ (p0 & 7);
    const int p1 = i1 >> 3, v1 = (i1 & 7) ^ (p1 & 7);
    const long ro0 = (long)(p0 * 2 + (v0 >> 2)) * 384 + (v0 & 3) * 8;
    const long ro1 = (long)(p1 * 2 + (v1 >> 2)) * 384 + (v1 & 3) * 8;
    const long aro0 = (long)m0 * 384 + ro0, aro1 = (long)m0 * 384 + ro1;
    const long bro0 = (long)n0 * 384 + ro0, bro1 = (long)n0 * 384 + ro1;

#define STAGE(kt) { const int _bf = (kt) % 3; const int _k0 = (kt) * 32; \
    __builtin_amdgcn_global_load_lds( \
        (const __attribute__((address_space(1))) void*)(A + aro0 + _k0), \
        (__attribute__((address_space(3))) void*)(As + _bf * 4096 + (size_t)i0 * 8), 16, 0, 0); \
    __builtin_amdgcn_global_load_lds( \
        (const __attribute__((address_space(1))) void*)(A + aro1 + _k0), \
        (__attribute__((address_space(3))) void*)(As + _bf * 4096 + (size_t)i1 * 8), 16, 0, 0); \
    __builtin_amdgcn_global_load_lds( \
        (const __attribute__((address_space(1))) void*)(Bb + bro0 + _k0), \
        (__attribute__((address_space(3))) void*)(Bs + _bf * 4096 + (size_t)i0 * 8), 16, 0, 0); \
    __builtin_amdgcn_global_load_lds( \
        (const __attribute__((address_space(1))) void*)(Bb + bro1 + _k0), \
        (__attribute__((address_space(3))) void*)(Bs + _bf * 4096 + (size_t)i1 * 8), 16, 0, 0); }

    // prologue: stage tiles 0 and 1 (8 loads/thread in flight)
    STAGE(0); STAGE(1);

    f32x16 acc[2][2];
    {
        f32x16 z = {};
        acc[0][0] = z; acc[0][1] = z; acc[1][0] = z; acc[1][1] = z;
    }

    #pragma unroll
    for (int kt = 0; kt < 12; ++kt) {
        // counted drain of tile kt's 4 loads (tile kt+1's stay in flight)
        if (kt < 11) asm volatile("s_waitcnt vmcnt(4)\n\ts_barrier" ::: "memory");
        else         asm volatile("s_waitcnt vmcnt(0)\n\ts_barrier" ::: "memory");

        const unsigned short* Ab = As + (kt % 3) * 4096;
        const unsigned short* Bl = Bs + (kt % 3) * 4096;

        bf16x8 av[2][2], bv[2][2];          // [kk][frag]
        #pragma unroll
        for (int kk = 0; kk < 2; ++kk) {
            int kslice = kk * 2 + khalf;
            #pragma unroll
            for (int mf = 0; mf < 2; ++mf) {
                int r = wr * 64 + mf * 32 + col;
                int p = r >> 1;
                int slot = (((r & 1) * 4 + kslice) ^ (p & 7));
                av[kk][mf] = *reinterpret_cast<const bf16x8*>(Ab + p * 64 + slot * 8);
            }
            #pragma unroll
            for (int nf = 0; nf < 2; ++nf) {
                int r = wc * 64 + nf * 32 + col;
                int p = r >> 1;
                int slot = (((r & 1) * 4 + kslice) ^ (p & 7));
                bv[kk][nf] = *reinterpret_cast<const bf16x8*>(Bl + p * 64 + slot * 8);
            }
        }
        if (kt < 10) STAGE(kt + 2);
        __builtin_amdgcn_s_setprio(1);
        #pragma unroll
        for (int kk = 0; kk < 2; ++kk)
            #pragma unroll
            for (int mf = 0; mf < 2; ++mf)
                #pragma unroll
                for (int nf = 0; nf < 2; ++nf)
                    acc[mf][nf] = __builtin_amdgcn_mfma_f32_32x32x16_bf16(
                        av[kk][mf], bv[kk][nf], acc[mf][nf], 0, 0, 0);
        __builtin_amdgcn_s_setprio(0);
    }
#undef STAGE

    // ---- epilogue: C layout col=lane&31, row=(reg&3)+8*(reg>>2)+4*(lane>>5)
    const int rowb = 4 * khalf;
    #pragma unroll
    for (int mf = 0; mf < 2; ++mf) {
        #pragma unroll
        for (int nf = 0; nf < 2; ++nf) {
            int n = n0 + wc * 64 + nf * 32 + col;
            f32x16 v = acc[mf][nf];
            if (m0 < 256) {
                #pragma unroll
                for (int q = 0; q < 4; ++q) {
                    int m = m0 + wr * 64 + mf * 32 + 8 * q + rowb;
                    us4 o = { f2bf(v[4 * q + 0] + bias[m]),
                              f2bf(v[4 * q + 1] + bias[m + 1]),
                              f2bf(v[4 * q + 2] + bias[m + 2]),
                              f2bf(v[4 * q + 3] + bias[m + 3]) };
                    *reinterpret_cast<us4*>(q_out + (((long)b * 4096 + n) << 8) + m) = o;
                }
            } else {
                #pragma unroll
                for (int reg = 0; reg < 16; ++reg) {
                    int m = m0 + wr * 64 + mf * 32 + 8 * (reg >> 2) + rowb + (reg & 3);
                    kv_out[((long)b * 768 + (m - 256)) * 4096 + n] = f2bf(v[reg] + bias[m]);
                }
            }
        }
    }
}

// ---------------- context (fused key softmax stats): part += exp(k)*v, psums = row sums ----------------
// No max-subtraction: |k| is small (BN output), exp(k) safe in f32; softmax ratio unchanged.
__global__ __launch_bounds__(256) void context_k(const unsigned short* __restrict__ kv,
                                                 float* __restrict__ part,
                                                 float* __restrict__ psums)
{
    __shared__ float lds[4][2048];
    __shared__ float slds[4][32];
    const int bh = blockIdx.y, ck = blockIdx.x;
    const int b = bh >> 3, h = bh & 7;
    const int tid = threadIdx.x, lane = tid & 63, w = tid >> 6;
    const int li = lane & 15, g = lane >> 4;
    const unsigned short* kb = kv + ((long)b * 768 + h * 32) * 4096;
    const unsigned short* vb = kv + ((long)b * 768 + 256 + h * 64) * 4096;
    f32x4 acc[2][4];
    #pragma unroll
    for (int i = 0; i < 2; ++i)
        #pragma unroll
        for (int j = 0; j < 4; ++j) acc[i][j] = (f32x4){0.f, 0.f, 0.f, 0.f};

    float s0 = 0.f, s1 = 0.f;
    const int nb0 = ck * 512 + w * 128 + g * 8;
    #pragma unroll
    for (int t = 0; t < 4; ++t) {
        int nb = nb0 + t * 32;
        bf16x8 r0 = *reinterpret_cast<const bf16x8*>(kb + (long)li * 4096 + nb);
        bf16x8 r1 = *reinterpret_cast<const bf16x8*>(kb + (long)(16 + li) * 4096 + nb);
        bf16x8 a0, a1;
        #pragma unroll
        for (int j = 0; j < 8; ++j) {
            float e0 = __expf(bf2f((unsigned short)r0[j]));
            float e1 = __expf(bf2f((unsigned short)r1[j]));
            a0[j] = (short)f2bf(e0); s0 += e0;
            a1[j] = (short)f2bf(e1); s1 += e1;
        }
        #pragma unroll
        for (int nf = 0; nf < 4; ++nf) {
            bf16x8 bv = *reinterpret_cast<const bf16x8*>(vb + (long)(nf * 16 + li) * 4096 + nb);
            acc[0][nf] = __builtin_amdgcn_mfma_f32_16x16x32_bf16(a0, bv, acc[0][nf], 0, 0, 0);
            acc[1][nf] = __builtin_amdgcn_mfma_f32_16x16x32_bf16(a1, bv, acc[1][nf], 0, 0, 0);
        }
    }
    // reduce row sums over the 4 g-groups (lanes li, li+16, li+32, li+48 share row li)
    s0 += __shfl_xor(s0, 16); s0 += __shfl_xor(s0, 32);
    s1 += __shfl_xor(s1, 16); s1 += __shfl_xor(s1, 32);
    if (lane < 16) { slds[w][lane] = s0; slds[w][16 + lane] = s1; }

    #pragma unroll
    for (int mf = 0; mf < 2; ++mf)
        #pragma unroll
        for (int nf = 0; nf < 4; ++nf)
            #pragma unroll
            for (int r = 0; r < 4; ++r) {
                int kd = mf * 16 + g * 4 + r, d = nf * 16 + li;
                lds[w][kd * 64 + d] = acc[mf][nf][r];
            }
    __syncthreads();
    for (int i = tid; i < 2048; i += 256)
        part[((long)ck * 64 + bh) * 2048 + i] = lds[0][i] + lds[1][i] + lds[2][i] + lds[3][i];
    if (tid < 32)
        psums[((long)ck * 64 + bh) * 32 + tid] =
            slds[0][tid] + slds[1][tid] + slds[2][tid] + slds[3][tid];
}

// ---------------- reduce partials, normalize by row sums -> ctxT[bh][d][kd] bf16 ----------------
__global__ __launch_bounds__(256) void ctx_reduce_k(const float* __restrict__ part,
                                                    const float* __restrict__ psums,
                                                    unsigned short* __restrict__ ctxT)
{
    int t = blockIdx.x * 256 + threadIdx.x;   // < 131072
    int bh = t >> 11, i = t & 2047;
    int kd = i & 31;
    float s = 0.f, den = 0.f;
    #pragma unroll
    for (int c = 0; c < 8; ++c) {
        s   += part[((long)c * 64 + bh) * 2048 + kd * 64 + (i >> 5)];
        den += psums[((long)c * 64 + bh) * 32 + kd];
    }
    ctxT[t] = f2bf(s / den);
}

// ---------------- fused proj v3: tall-M block (M=384), softmax+attend once, GEMM ----------------
// grid (32 n-blocks, 8 b), 512 threads = 8 waves. LDS = 112 KB -> 1 block/CU.
__global__ __launch_bounds__(512, 2) void proj_fused_k(
    const unsigned short* __restrict__ Wpf,   // [384][512] bf16, k = h*64+d
    const unsigned short* __restrict__ qT,    // [b][4096][256] bf16 (raw q, pre-softmax)
    const unsigned short* __restrict__ ctxT,  // [b*8+h][64 d][32 kd] bf16
    const float* __restrict__ bp,
    float* __restrict__ out)                  // [b][384][4096] f32
{
    __shared__ unsigned short Bsh[128 * 64];  // relu(attend) tile for current head, swizzled
    __shared__ unsigned short As[2][384 * 64];
    const int tid = threadIdx.x, lane = tid & 63, w = tid >> 6;
    const int li = lane & 15, g = lane >> 4;
    const int b = blockIdx.y, n0 = blockIdx.x * 128;

#define PROJ_STAGE(buf, s) { \
    _Pragma("unroll") \
    for (int j = 0; j < 6; ++j) { \
        int idx = j * 512 + tid; \
        int r = idx >> 3; \
        int ls = ((idx & 7) ^ (r & 7)) * 8; \
        __builtin_amdgcn_global_load_lds( \
            (const __attribute__((address_space(1))) void*)(Wpf + (long)r * 512 + (s) * 64 + ls), \
            (__attribute__((address_space(3))) void*)(As[buf] + (size_t)idx * 8), 16, 0, 0); \
    } }

    PROJ_STAGE(0, 0);

    f32x4 acc[3][8];
    #pragma unroll
    for (int i = 0; i < 3; ++i)
        #pragma unroll
        for (int j = 0; j < 8; ++j) acc[i][j] = (f32x4){0.f, 0.f, 0.f, 0.f};

    for (int s = 0; s < 8; ++s) {               // K-step s == head s
        // ---- attend (once per block): A = ctxT_s, B = softmax(q) in-register.
        const unsigned short* cb = ctxT + ((long)b * 8 + s) * 2048;
        bf16x8 ca[4], pb;
        #pragma unroll
        for (int df = 0; df < 4; ++df)
            ca[df] = *reinterpret_cast<const bf16x8*>(cb + (df * 16 + li) * 32 + g * 8);
        {
            int n = n0 + w * 16 + li;
            bf16x8 r = *reinterpret_cast<const bf16x8*>(
                qT + (((long)b * 4096 + n) << 8) + s * 32 + g * 8);
            float f[8];
            float mx = -1e30f;
            #pragma unroll
            for (int j = 0; j < 8; ++j) { f[j] = bf2f((unsigned short)r[j]); mx = fmaxf(mx, f[j]); }
            mx = fmaxf(mx, __shfl_xor(mx, 16));
            mx = fmaxf(mx, __shfl_xor(mx, 32));
            float sm = 0.f;
            #pragma unroll
            for (int j = 0; j < 8; ++j) { f[j] = __expf(f[j] - mx); sm += f[j]; }
            sm += __shfl_xor(sm, 16);
            sm += __shfl_xor(sm, 32);
            float inv = 1.f / sm;
            #pragma unroll
            for (int j = 0; j < 8; ++j) pb[j] = (short)f2bf(f[j] * inv);
        }
        us4 bw[4];
        #pragma unroll
        for (int df = 0; df < 4; ++df) {
            f32x4 d = (f32x4){0.f, 0.f, 0.f, 0.f};
            d = __builtin_amdgcn_mfma_f32_16x16x32_bf16(ca[df], pb, d, 0, 0, 0);
            bw[df] = (us4){ f2bf(fmaxf(d.x, 0.f)), f2bf(fmaxf(d.y, 0.f)),
                            f2bf(fmaxf(d.z, 0.f)), f2bf(fmaxf(d.w, 0.f)) };
        }

        __syncthreads();   // (A) prior step's Bsh/As reads done; As[s&1] data landed (vmcnt0)

        if (s < 7) PROJ_STAGE((s + 1) & 1, s + 1);   // As[(s+1)&1] readers finished at (A)

        // ---- write relu(attend) tile swizzled: Bsh[n][d], granule-8 XOR by (n&7)
        #pragma unroll
        for (int df = 0; df < 4; ++df) {
            int n = w * 16 + li;
            int slot = (df * 2 + (g >> 1)) ^ (n & 7);
            *reinterpret_cast<us4*>(Bsh + n * 64 + slot * 8 + (g & 1) * 4) = bw[df];
        }

        // (B) lgkm-only barrier: Bsh visible, As[(s+1)&1] stage stays in flight (T4)
        asm volatile("s_waitcnt lgkmcnt(0)\n\ts_barrier" ::: "memory");
        __builtin_amdgcn_sched_barrier(0);

        // ---- main GEMM MFMAs: wave w owns m-rows w*48..w*48+48 x n 0..128
        const unsigned short* Ab = As[s & 1];
        #pragma unroll
        for (int kk = 0; kk < 2; ++kk) {
            bf16x8 av[3], bv[8];
            #pragma unroll
            for (int mf = 0; mf < 3; ++mf) {
                int row = w * 48 + mf * 16 + li;
                int ps = ((kk * 4 + g) ^ (row & 7)) * 8;
                av[mf] = *reinterpret_cast<const bf16x8*>(Ab + row * 64 + ps);
            }
            #pragma unroll
            for (int nf = 0; nf < 8; ++nf) {
                int nn = nf * 16 + li;
                int ps = ((kk * 4 + g) ^ (nn & 7)) * 8;
                bv[nf] = *reinterpret_cast<const bf16x8*>(Bsh + nn * 64 + ps);
            }
            #pragma unroll
            for (int mf = 0; mf < 3; ++mf)
                #pragma unroll
                for (int nf = 0; nf < 8; ++nf)
                    acc[mf][nf] = __builtin_amdgcn_mfma_f32_16x16x32_bf16(av[mf], bv[nf], acc[mf][nf], 0, 0, 0);
        }
    }
#undef PROJ_STAGE

    #pragma unroll
    for (int mf = 0; mf < 3; ++mf) {
        int m = w * 48 + mf * 16 + g * 4;
        #pragma unroll
        for (int nf = 0; nf < 8; ++nf) {
            int n = n0 + nf * 16 + li;
            f32x4 v = acc[mf][nf];
            #pragma unroll
            for (int r = 0; r < 4; ++r)
                out[((long)b * 384 + m + r) * 4096 + n] = v[r] + bp[m + r];
        }
    }
}

// ---------------- launch ----------------
extern "C" void kernel_launch(void* const* d_in, const int* in_sizes, int n_in,
                              void* d_out, int out_size, void* d_ws, size_t ws_size,
                              hipStream_t stream) {
    (void)in_sizes; (void)n_in; (void)out_size; (void)ws_size;
    const float* x  = (const float*)d_in[0];
    const float* Wq = (const float*)d_in[1];
    const float* sq = (const float*)d_in[2];
    const float* bq = (const float*)d_in[3];
    const float* Wk = (const float*)d_in[4];
    const float* sk = (const float*)d_in[5];
    const float* bk = (const float*)d_in[6];
    const float* Wv = (const float*)d_in[7];
    const float* sv = (const float*)d_in[8];
    const float* bv = (const float*)d_in[9];
    const float* Wp = (const float*)d_in[10];
    const float* sp = (const float*)d_in[11];
    const float* bp = (const float*)d_in[12];
    float* out = (float*)d_out;

    char* wsb = (char*)d_ws;
    unsigned short* Wqkv  = (unsigned short*)(wsb);              // 786432 B
    unsigned short* Wpf   = (unsigned short*)(wsb + 786432);     // 393216 B
    float*          bqkv  = (float*)(wsb + 1179648);             // 4096 B
    unsigned short* ctxT  = (unsigned short*)(wsb + 1183744);    // 262144 B
    float*          part  = (float*)(wsb + 1445888);             // 4194304 B
    float*          psums = (float*)(wsb + 5640192);             // 65536 B
    unsigned short* xT    = (unsigned short*)(wsb + 5705728);    // 25165824 B
    unsigned short* qT    = (unsigned short*)(wsb + 30871552);   // 16777216 B
    unsigned short* kv    = (unsigned short*)(wsb + 47648768);   // 50331648 B -> ~98 MB total

    fold_weights_k<<<2308, 256, 0, stream>>>(Wq, sq, bq, Wk, sk, bk, Wv, sv, bv, Wp, sp,
                                             Wqkv, Wpf, bqkv);
    transpose_x_k<<<dim3(64, 6, 8), 256, 0, stream>>>(x, xT);
    gemm_qkv_k<<<dim3(32, 8, 8), 256, 0, stream>>>(Wqkv, xT, bqkv, qT, kv);
    context_k<<<dim3(8, 64), 256, 0, stream>>>(kv, part, psums);
    ctx_reduce_k<<<512, 256, 0, stream>>>(part, psums, ctxT);
    proj_fused_k<<<dim3(32, 8), 512, 0, stream>>>(Wpf, qT, ctxT, bp, out);
}

// Round 10
// 101.881 us; speedup vs baseline: 1.1425x; 1.1425x over previous
//
#include <hip/hip_runtime.h>

typedef __attribute__((ext_vector_type(8))) short bf16x8;
typedef __attribute__((ext_vector_type(4))) float f32x4;
typedef __attribute__((ext_vector_type(4))) unsigned short us4;

__device__ __forceinline__ unsigned short f2bf(float f) {
    unsigned int u = __builtin_bit_cast(unsigned int, f);
    u = (u + 0x7FFFu + ((u >> 16) & 1u)) >> 16;
    return (unsigned short)u;
}
__device__ __forceinline__ float bf2f(unsigned short h) {
    return __builtin_bit_cast(float, (unsigned int)h << 16);
}

// ---------------- fold BN into weights, emit bf16; per-head packed row order ----------------
// WqkvP row r: head=r>>7, t=r&127: t<32 -> q ch head*32+t; t<64 -> k ch head*32+t-32; else v ch head*64+t-64.
__global__ __launch_bounds__(256) void fold_weights_k(
    const float* __restrict__ Wq, const float* __restrict__ sq, const float* __restrict__ bq,
    const float* __restrict__ Wk, const float* __restrict__ sk, const float* __restrict__ bk,
    const float* __restrict__ Wv, const float* __restrict__ sv, const float* __restrict__ bv,
    const float* __restrict__ Wp, const float* __restrict__ sp,
    unsigned short* __restrict__ WqkvP, unsigned short* __restrict__ Wpf, float* __restrict__ bqkvP)
{
    int i = blockIdx.x * 256 + threadIdx.x;
    if (i < 393216) {                       // WqkvP [1024][384]
        int r = i / 384, c = i - r * 384;
        int head = r >> 7, t = r & 127;
        float w, s;
        if (t < 32)      { int ch = head * 32 + t;        w = Wq[ch * 384 + c]; s = sq[ch]; }
        else if (t < 64) { int ch = head * 32 + (t - 32); w = Wk[ch * 384 + c]; s = sk[ch]; }
        else             { int ch = head * 64 + (t - 64); w = Wv[ch * 384 + c]; s = sv[ch]; }
        WqkvP[i] = f2bf(w * s);
    } else if (i < 589824) {                // Wpf [384][512]
        int j = i - 393216;
        Wpf[j] = f2bf(Wp[j] * sp[j >> 9]);
    } else if (i < 590848) {
        int r = i - 589824;
        int head = r >> 7, t = r & 127;
        bqkvP[r] = (t < 32) ? bq[head * 32 + t]
                 : (t < 64) ? bk[head * 32 + (t - 32)]
                            : bv[head * 64 + (t - 64)];
    }
}

// ---------------- x [b][384][4096] f32 -> xT [b][4096][384] bf16 (vectorized) ----------------
__global__ __launch_bounds__(256) void transpose_x_k(const float* __restrict__ x,
                                                     unsigned short* __restrict__ xT)
{
    __shared__ unsigned short t[64][72];
    const int b = blockIdx.z, cb = blockIdx.y << 6, nb = blockIdx.x << 6;
    const int tid = threadIdx.x;
    const float* xb = x + ((long)b * 384 + cb) * 4096 + nb;
    const int n4 = (tid & 15) * 4;
    #pragma unroll
    for (int p = 0; p < 4; ++p) {
        int c = (tid >> 4) + p * 16;
        float4 v = *reinterpret_cast<const float4*>(xb + (long)c * 4096 + n4);
        us4 o = { f2bf(v.x), f2bf(v.y), f2bf(v.z), f2bf(v.w) };
        *reinterpret_cast<us4*>(&t[c][n4]) = o;
    }
    __syncthreads();
    const int c4 = (tid & 15) * 4;
    unsigned short* ob = xT + ((long)b * 4096 + nb) * 384 + cb;
    #pragma unroll
    for (int p = 0; p < 4; ++p) {
        int n = (tid >> 4) + p * 16;
        us4 o = { t[c4][n], t[c4 + 1][n], t[c4 + 2][n], t[c4 + 3][n] };
        *reinterpret_cast<us4*>(ob + (long)n * 384 + c4) = o;
    }
}

// ---------------- fused QKV GEMM + context partials ----------------
// grid (32 n-chunks, 8 heads, 8 b), 256 threads = 4 waves. LDS 48 KB -> 3 blocks/CU.
// Hot loop = R8's proven conflict-free 3-buf BK=32 pipeline (16x16x32 MFMA).
// Epilogue: q -> qT; exp(k)->Ksh LDS + row sums; v -> Vsh LDS; mini-GEMM exp(k)@v^T
// over n=128 -> part[chunk][bh][32*64] + psums. kv never touches HBM.
__global__ __launch_bounds__(256, 3) void gemm_qkv_k(
    const unsigned short* __restrict__ A,     // WqkvP [1024][384] head-packed
    const unsigned short* __restrict__ Bt,    // xT    [b][4096][384]
    const float* __restrict__ bias,           // bqkvP
    unsigned short* __restrict__ q_out,       // qT [b][4096][256]
    float* __restrict__ part,                 // [32][64][2048]
    float* __restrict__ psums)                // [32][64][32]
{
    __shared__ unsigned short As[3 * 4096];   // 3 x 128 rows x 32 k; reused as Ksh/Vsh
    __shared__ unsigned short Bs[3 * 4096];   // reused for psl
    const int tid = threadIdx.x;
    const int lane = tid & 63;
    const int w = tid >> 6, wr = w >> 1, wc = w & 1;
    const int li = lane & 15, g = lane >> 4;
    const int b = blockIdx.z, head = blockIdx.y, chunk = blockIdx.x;
    const int n0 = chunk * 128, m0 = head * 128;
    const unsigned short* Bb = Bt + (long)b * 4096 * 384;

    // staging granule map (inverse of read swizzle): granule i -> (row, k-slice)
    const int i0 = tid, i1 = tid + 256;
    const int p0 = i0 >> 3, v0 = (i0 & 7) ^ (p0 & 7);
    const int p1 = i1 >> 3, v1 = (i1 & 7) ^ (p1 & 7);
    const long ro0 = (long)(p0 * 2 + (v0 >> 2)) * 384 + (v0 & 3) * 8;
    const long ro1 = (long)(p1 * 2 + (v1 >> 2)) * 384 + (v1 & 3) * 8;
    const long aro0 = (long)m0 * 384 + ro0, aro1 = (long)m0 * 384 + ro1;
    const long bro0 = (long)n0 * 384 + ro0, bro1 = (long)n0 * 384 + ro1;

#define STAGE(kt) { const int _bf = (kt) % 3; const int _k0 = (kt) * 32; \
    __builtin_amdgcn_global_load_lds( \
        (const __attribute__((address_space(1))) void*)(A + aro0 + _k0), \
        (__attribute__((address_space(3))) void*)(As + _bf * 4096 + (size_t)i0 * 8), 16, 0, 0); \
    __builtin_amdgcn_global_load_lds( \
        (const __attribute__((address_space(1))) void*)(A + aro1 + _k0), \
        (__attribute__((address_space(3))) void*)(As + _bf * 4096 + (size_t)i1 * 8), 16, 0, 0); \
    __builtin_amdgcn_global_load_lds( \
        (const __attribute__((address_space(1))) void*)(Bb + bro0 + _k0), \
        (__attribute__((address_space(3))) void*)(Bs + _bf * 4096 + (size_t)i0 * 8), 16, 0, 0); \
    __builtin_amdgcn_global_load_lds( \
        (const __attribute__((address_space(1))) void*)(Bb + bro1 + _k0), \
        (__attribute__((address_space(3))) void*)(Bs + _bf * 4096 + (size_t)i1 * 8), 16, 0, 0); }

    STAGE(0); STAGE(1);

    f32x4 acc[4][4];
    #pragma unroll
    for (int i = 0; i < 4; ++i)
        #pragma unroll
        for (int j = 0; j < 4; ++j) acc[i][j] = (f32x4){0.f, 0.f, 0.f, 0.f};

    #pragma unroll
    for (int kt = 0; kt < 12; ++kt) {
        if (kt < 11) asm volatile("s_waitcnt vmcnt(4)\n\ts_barrier" ::: "memory");
        else         asm volatile("s_waitcnt vmcnt(0)\n\ts_barrier" ::: "memory");

        const unsigned short* Ab = As + (kt % 3) * 4096;
        const unsigned short* Bl = Bs + (kt % 3) * 4096;

        bf16x8 av[4], bv[4];
        #pragma unroll
        for (int mf = 0; mf < 4; ++mf) {
            int r = wr * 64 + mf * 16 + li;
            int p = r >> 1;
            int slot = (((r & 1) * 4 + g) ^ (p & 7));
            av[mf] = *reinterpret_cast<const bf16x8*>(Ab + p * 64 + slot * 8);
        }
        #pragma unroll
        for (int nf = 0; nf < 4; ++nf) {
            int r = wc * 64 + nf * 16 + li;
            int p = r >> 1;
            int slot = (((r & 1) * 4 + g) ^ (p & 7));
            bv[nf] = *reinterpret_cast<const bf16x8*>(Bl + p * 64 + slot * 8);
        }
        if (kt < 10) STAGE(kt + 2);
        __builtin_amdgcn_s_setprio(1);
        #pragma unroll
        for (int mf = 0; mf < 4; ++mf)
            #pragma unroll
            for (int nf = 0; nf < 4; ++nf)
                acc[mf][nf] = __builtin_amdgcn_mfma_f32_16x16x32_bf16(av[mf], bv[nf], acc[mf][nf], 0, 0, 0);
        __builtin_amdgcn_s_setprio(0);
    }
#undef STAGE

    __syncthreads();   // hot-loop LDS reads done; As/Bs now reusable

    // LDS reuse: Ksh [32][128] = As[0..4095], Vsh [64][128] = As[4096..12287]
    unsigned short* Ksh = As;
    unsigned short* Vsh = As + 4096;
    float* psl = reinterpret_cast<float*>(Bs);   // [2][32]

    // swizzled elem index within a 256B row: row*128 + (((n>>3)^(row&7))<<3 | (n&7))
    if (wr == 0) {
        // ---- q rows (mf 0,1): packed us4 to qT
        #pragma unroll
        for (int mf = 0; mf < 2; ++mf) {
            int ml = mf * 16 + g * 4;                  // 0..31
            #pragma unroll
            for (int nf = 0; nf < 4; ++nf) {
                int n = n0 + wc * 64 + nf * 16 + li;
                f32x4 v = acc[mf][nf];
                us4 o = { f2bf(v.x + bias[m0 + ml]),     f2bf(v.y + bias[m0 + ml + 1]),
                          f2bf(v.z + bias[m0 + ml + 2]), f2bf(v.w + bias[m0 + ml + 3]) };
                *reinterpret_cast<us4*>(q_out + (((long)b * 4096 + n) << 8) + head * 32 + ml) = o;
            }
        }
        // ---- k rows (mf 2,3): exp into Ksh + row sums
        float rs[2][4] = {{0.f,0.f,0.f,0.f},{0.f,0.f,0.f,0.f}};
        #pragma unroll
        for (int mm = 0; mm < 2; ++mm) {
            #pragma unroll
            for (int nf = 0; nf < 4; ++nf) {
                int nl = wc * 64 + nf * 16 + li;
                f32x4 v = acc[mm + 2][nf];
                #pragma unroll
                for (int r = 0; r < 4; ++r) {
                    int kd = mm * 16 + g * 4 + r;
                    float e = __expf(v[r] + bias[m0 + 32 + kd]);
                    rs[mm][r] += e;
                    Ksh[kd * 128 + ((((nl >> 3) ^ (kd & 7)) << 3) | (nl & 7))] = f2bf(e);
                }
            }
        }
        #pragma unroll
        for (int mm = 0; mm < 2; ++mm)
            #pragma unroll
            for (int r = 0; r < 4; ++r) {
                float s = rs[mm][r];
                s += __shfl_xor(s, 1); s += __shfl_xor(s, 2);
                s += __shfl_xor(s, 4); s += __shfl_xor(s, 8);
                if (li == 0) psl[wc * 32 + mm * 16 + g * 4 + r] = s;
            }
    } else {
        // ---- v rows (all mf): bias, bf16 into Vsh
        #pragma unroll
        for (int mf = 0; mf < 4; ++mf) {
            #pragma unroll
            for (int nf = 0; nf < 4; ++nf) {
                int nl = wc * 64 + nf * 16 + li;
                f32x4 v = acc[mf][nf];
                #pragma unroll
                for (int r = 0; r < 4; ++r) {
                    int d = mf * 16 + g * 4 + r;
                    Vsh[d * 128 + ((((nl >> 3) ^ (d & 7)) << 3) | (nl & 7))] =
                        f2bf(v[r] + bias[m0 + 64 + d]);
                }
            }
        }
    }
    __syncthreads();

    // ---- mini-GEMM: ctx_part[kd 32][d 64] = Ksh @ Vsh^T over n=128; wave w owns d-cols w*16..+16
    f32x4 c2[2] = {(f32x4){0.f,0.f,0.f,0.f}, (f32x4){0.f,0.f,0.f,0.f}};
    #pragma unroll
    for (int ks = 0; ks < 4; ++ks) {
        int rd = w * 16 + li;
        bf16x8 a0 = *reinterpret_cast<const bf16x8*>(Ksh + li * 128        + ((((ks * 4 + g) ^ (li & 7)) << 3)));
        bf16x8 a1 = *reinterpret_cast<const bf16x8*>(Ksh + (16 + li) * 128 + ((((ks * 4 + g) ^ ((16 + li) & 7)) << 3)));
        bf16x8 bb = *reinterpret_cast<const bf16x8*>(Vsh + rd * 128        + ((((ks * 4 + g) ^ (rd & 7)) << 3)));
        c2[0] = __builtin_amdgcn_mfma_f32_16x16x32_bf16(a0, bb, c2[0], 0, 0, 0);
        c2[1] = __builtin_amdgcn_mfma_f32_16x16x32_bf16(a1, bb, c2[1], 0, 0, 0);
    }
    const int bh = b * 8 + head;
    const long pbase = ((long)chunk * 64 + bh) * 2048;
    #pragma unroll
    for (int mm = 0; mm < 2; ++mm)
        #pragma unroll
        for (int r = 0; r < 4; ++r)
            part[pbase + (mm * 16 + g * 4 + r) * 64 + w * 16 + li] = c2[mm][r];
    if (tid < 32)
        psums[((long)chunk * 64 + bh) * 32 + tid] = psl[tid] + psl[32 + tid];
}

// ---------------- reduce 32 chunks, normalize -> ctxT[bh][d][kd] bf16 ----------------
__global__ __launch_bounds__(256) void ctx_reduce_k(const float* __restrict__ part,
                                                    const float* __restrict__ psums,
                                                    unsigned short* __restrict__ ctxT)
{
    int t = blockIdx.x * 256 + threadIdx.x;   // < 131072
    int bh = t >> 11, i = t & 2047;
    int kd = i & 31, d = i >> 5;
    float s = 0.f, den = 0.f;
    #pragma unroll
    for (int c = 0; c < 32; ++c) {
        s   += part[((long)c * 64 + bh) * 2048 + kd * 64 + d];
        den += psums[((long)c * 64 + bh) * 32 + kd];
    }
    ctxT[t] = f2bf(s / den);
}

// ---------------- fused proj: tall-M block (M=384), softmax+attend once, GEMM ----------------
__global__ __launch_bounds__(512, 2) void proj_fused_k(
    const unsigned short* __restrict__ Wpf,   // [384][512] bf16, k = h*64+d
    const unsigned short* __restrict__ qT,    // [b][4096][256] bf16 (raw q, pre-softmax)
    const unsigned short* __restrict__ ctxT,  // [b*8+h][64 d][32 kd] bf16
    const float* __restrict__ bp,
    float* __restrict__ out)                  // [b][384][4096] f32
{
    __shared__ unsigned short Bsh[128 * 64];
    __shared__ unsigned short As[2][384 * 64];
    const int tid = threadIdx.x, lane = tid & 63, w = tid >> 6;
    const int li = lane & 15, g = lane >> 4;
    const int b = blockIdx.y, n0 = blockIdx.x * 128;

#define PROJ_STAGE(buf, s) { \
    _Pragma("unroll") \
    for (int j = 0; j < 6; ++j) { \
        int idx = j * 512 + tid; \
        int r = idx >> 3; \
        int ls = ((idx & 7) ^ (r & 7)) * 8; \
        __builtin_amdgcn_global_load_lds( \
            (const __attribute__((address_space(1))) void*)(Wpf + (long)r * 512 + (s) * 64 + ls), \
            (__attribute__((address_space(3))) void*)(As[buf] + (size_t)idx * 8), 16, 0, 0); \
    } }

    PROJ_STAGE(0, 0);

    f32x4 acc[3][8];
    #pragma unroll
    for (int i = 0; i < 3; ++i)
        #pragma unroll
        for (int j = 0; j < 8; ++j) acc[i][j] = (f32x4){0.f, 0.f, 0.f, 0.f};

    for (int s = 0; s < 8; ++s) {
        const unsigned short* cb = ctxT + ((long)b * 8 + s) * 2048;
        bf16x8 ca[4], pb;
        #pragma unroll
        for (int df = 0; df < 4; ++df)
            ca[df] = *reinterpret_cast<const bf16x8*>(cb + (df * 16 + li) * 32 + g * 8);
        {
            int n = n0 + w * 16 + li;
            bf16x8 r = *reinterpret_cast<const bf16x8*>(
                qT + (((long)b * 4096 + n) << 8) + s * 32 + g * 8);
            float f[8];
            float mx = -1e30f;
            #pragma unroll
            for (int j = 0; j < 8; ++j) { f[j] = bf2f((unsigned short)r[j]); mx = fmaxf(mx, f[j]); }
            mx = fmaxf(mx, __shfl_xor(mx, 16));
            mx = fmaxf(mx, __shfl_xor(mx, 32));
            float sm = 0.f;
            #pragma unroll
            for (int j = 0; j < 8; ++j) { f[j] = __expf(f[j] - mx); sm += f[j]; }
            sm += __shfl_xor(sm, 16);
            sm += __shfl_xor(sm, 32);
            float inv = 1.f / sm;
            #pragma unroll
            for (int j = 0; j < 8; ++j) pb[j] = (short)f2bf(f[j] * inv);
        }
        us4 bw[4];
        #pragma unroll
        for (int df = 0; df < 4; ++df) {
            f32x4 d = (f32x4){0.f, 0.f, 0.f, 0.f};
            d = __builtin_amdgcn_mfma_f32_16x16x32_bf16(ca[df], pb, d, 0, 0, 0);
            bw[df] = (us4){ f2bf(fmaxf(d.x, 0.f)), f2bf(fmaxf(d.y, 0.f)),
                            f2bf(fmaxf(d.z, 0.f)), f2bf(fmaxf(d.w, 0.f)) };
        }

        __syncthreads();

        if (s < 7) PROJ_STAGE((s + 1) & 1, s + 1);

        #pragma unroll
        for (int df = 0; df < 4; ++df) {
            int n = w * 16 + li;
            int slot = (df * 2 + (g >> 1)) ^ (n & 7);
            *reinterpret_cast<us4*>(Bsh + n * 64 + slot * 8 + (g & 1) * 4) = bw[df];
        }

        asm volatile("s_waitcnt lgkmcnt(0)\n\ts_barrier" ::: "memory");
        __builtin_amdgcn_sched_barrier(0);

        const unsigned short* Ab = As[s & 1];
        #pragma unroll
        for (int kk = 0; kk < 2; ++kk) {
            bf16x8 av[3], bv[8];
            #pragma unroll
            for (int mf = 0; mf < 3; ++mf) {
                int row = w * 48 + mf * 16 + li;
                int ps = ((kk * 4 + g) ^ (row & 7)) * 8;
                av[mf] = *reinterpret_cast<const bf16x8*>(Ab + row * 64 + ps);
            }
            #pragma unroll
            for (int nf = 0; nf < 8; ++nf) {
                int nn = nf * 16 + li;
                int ps = ((kk * 4 + g) ^ (nn & 7)) * 8;
                bv[nf] = *reinterpret_cast<const bf16x8*>(Bsh + nn * 64 + ps);
            }
            #pragma unroll
            for (int mf = 0; mf < 3; ++mf)
                #pragma unroll
                for (int nf = 0; nf < 8; ++nf)
                    acc[mf][nf] = __builtin_amdgcn_mfma_f32_16x16x32_bf16(av[mf], bv[nf], acc[mf][nf], 0, 0, 0);
        }
    }
#undef PROJ_STAGE

    #pragma unroll
    for (int mf = 0; mf < 3; ++mf) {
        int m = w * 48 + mf * 16 + g * 4;
        #pragma unroll
        for (int nf = 0; nf < 8; ++nf) {
            int n = n0 + nf * 16 + li;
            f32x4 v = acc[mf][nf];
            #pragma unroll
            for (int r = 0; r < 4; ++r)
                out[((long)b * 384 + m + r) * 4096 + n] = v[r] + bp[m + r];
        }
    }
}

// ---------------- launch ----------------
extern "C" void kernel_launch(void* const* d_in, const int* in_sizes, int n_in,
                              void* d_out, int out_size, void* d_ws, size_t ws_size,
                              hipStream_t stream) {
    (void)in_sizes; (void)n_in; (void)out_size; (void)ws_size;
    const float* x  = (const float*)d_in[0];
    const float* Wq = (const float*)d_in[1];
    const float* sq = (const float*)d_in[2];
    const float* bq = (const float*)d_in[3];
    const float* Wk = (const float*)d_in[4];
    const float* sk = (const float*)d_in[5];
    const float* bk = (const float*)d_in[6];
    const float* Wv = (const float*)d_in[7];
    const float* sv = (const float*)d_in[8];
    const float* bv = (const float*)d_in[9];
    const float* Wp = (const float*)d_in[10];
    const float* sp = (const float*)d_in[11];
    const float* bp = (const float*)d_in[12];
    float* out = (float*)d_out;

    char* wsb = (char*)d_ws;
    unsigned short* Wqkv  = (unsigned short*)(wsb);              // 786432 B
    unsigned short* Wpf   = (unsigned short*)(wsb + 786432);     // 393216 B
    float*          bqkv  = (float*)(wsb + 1179648);             // 4096 B
    unsigned short* ctxT  = (unsigned short*)(wsb + 1183744);    // 262144 B
    float*          part  = (float*)(wsb + 1445888);             // 16777216 B
    float*          psums = (float*)(wsb + 18223104);            // 262144 B
    unsigned short* xT    = (unsigned short*)(wsb + 18485248);   // 25165824 B
    unsigned short* qT    = (unsigned short*)(wsb + 43651072);   // 16777216 B -> 60.4 MB total

    fold_weights_k<<<2308, 256, 0, stream>>>(Wq, sq, bq, Wk, sk, bk, Wv, sv, bv, Wp, sp,
                                             Wqkv, Wpf, bqkv);
    transpose_x_k<<<dim3(64, 6, 8), 256, 0, stream>>>(x, xT);
    gemm_qkv_k<<<dim3(32, 8, 8), 256, 0, stream>>>(Wqkv, xT, bqkv, qT, part, psums);
    ctx_reduce_k<<<512, 256, 0, stream>>>(part, psums, ctxT);
    proj_fused_k<<<dim3(32, 8), 512, 0, stream>>>(Wpf, qT, ctxT, bp, out);
}

// Round 11
// 98.612 us; speedup vs baseline: 1.1804x; 1.0331x over previous
//
#include <hip/hip_runtime.h>

typedef __attribute__((ext_vector_type(8))) short bf16x8;
typedef __attribute__((ext_vector_type(4))) float f32x4;
typedef __attribute__((ext_vector_type(4))) unsigned short us4;

__device__ __forceinline__ unsigned short f2bf(float f) {
    unsigned int u = __builtin_bit_cast(unsigned int, f);
    u = (u + 0x7FFFu + ((u >> 16) & 1u)) >> 16;
    return (unsigned short)u;
}
__device__ __forceinline__ float bf2f(unsigned short h) {
    return __builtin_bit_cast(float, (unsigned int)h << 16);
}

// ---------------- fold BN into weights, emit bf16; per-head packed row order ----------------
__global__ __launch_bounds__(256) void fold_weights_k(
    const float* __restrict__ Wq, const float* __restrict__ sq, const float* __restrict__ bq,
    const float* __restrict__ Wk, const float* __restrict__ sk, const float* __restrict__ bk,
    const float* __restrict__ Wv, const float* __restrict__ sv, const float* __restrict__ bv,
    const float* __restrict__ Wp, const float* __restrict__ sp,
    unsigned short* __restrict__ WqkvP, unsigned short* __restrict__ Wpf, float* __restrict__ bqkvP)
{
    int i = blockIdx.x * 256 + threadIdx.x;
    if (i < 393216) {                       // WqkvP [1024][384]
        int r = i / 384, c = i - r * 384;
        int head = r >> 7, t = r & 127;
        float w, s;
        if (t < 32)      { int ch = head * 32 + t;        w = Wq[ch * 384 + c]; s = sq[ch]; }
        else if (t < 64) { int ch = head * 32 + (t - 32); w = Wk[ch * 384 + c]; s = sk[ch]; }
        else             { int ch = head * 64 + (t - 64); w = Wv[ch * 384 + c]; s = sv[ch]; }
        WqkvP[i] = f2bf(w * s);
    } else if (i < 589824) {                // Wpf [384][512]
        int j = i - 393216;
        Wpf[j] = f2bf(Wp[j] * sp[j >> 9]);
    } else if (i < 590848) {
        int r = i - 589824;
        int head = r >> 7, t = r & 127;
        bqkvP[r] = (t < 32) ? bq[head * 32 + t]
                 : (t < 64) ? bk[head * 32 + (t - 32)]
                            : bv[head * 64 + (t - 64)];
    }
}

// ---------------- fused QKV GEMM (x read directly, transpose in-LDS) + context partials ----------------
// grid (32 n-chunks, 8 heads, 8 b), 256 threads = 4 waves. LDS 48 KB -> 3 blocks/CU.
// A staged via global_load_lds (proven layout). B staged via regs: wave w reads 8 channels
// of x (f32, coalesced float2/lane), packs bf16, ds_write_b128 into the SAME swizzled
// geometry (write slot = ((n&1)*4+w)^(p&7) == read slot with g==w -> conflict-free).
__global__ __launch_bounds__(256, 3) void gemm_qkv_k(
    const unsigned short* __restrict__ A,     // WqkvP [1024][384] head-packed
    const float* __restrict__ x,              // [b][384][4096] f32
    const float* __restrict__ bias,           // bqkvP
    unsigned short* __restrict__ q_out,       // qT [b][4096][256]
    float* __restrict__ part,                 // [32][64][2048]
    float* __restrict__ psums)                // [32][64][32]
{
    __shared__ unsigned short As[3 * 4096];   // 3 x 128 rows x 32 k; reused as Ksh/Vsh
    __shared__ unsigned short Bs[3 * 4096];   // reused for psl
    const int tid = threadIdx.x;
    const int lane = tid & 63;
    const int w = tid >> 6, wr = w >> 1, wc = w & 1;
    const int li = lane & 15, g = lane >> 4;
    const int b = blockIdx.z, head = blockIdx.y, chunk = blockIdx.x;
    const int n0 = chunk * 128, m0 = head * 128;
    const float* xb = x + (long)b * 384 * 4096 + n0 + 2 * lane;  // + c*4096 indexes channel

    // A staging granule map (inverse of read swizzle)
    const int i0 = tid, i1 = tid + 256;
    const int p0 = i0 >> 3, v0 = (i0 & 7) ^ (p0 & 7);
    const int p1 = i1 >> 3, v1 = (i1 & 7) ^ (p1 & 7);
    const long aro0 = (long)m0 * 384 + (long)(p0 * 2 + (v0 >> 2)) * 384 + (v0 & 3) * 8;
    const long aro1 = (long)m0 * 384 + (long)(p1 * 2 + (v1 >> 2)) * 384 + (v1 & 3) * 8;

#define ISSUE_A(kt) { const int _bf = (kt) % 3; const int _k0 = (kt) * 32; \
    __builtin_amdgcn_global_load_lds( \
        (const __attribute__((address_space(1))) void*)(A + aro0 + _k0), \
        (__attribute__((address_space(3))) void*)(As + _bf * 4096 + (size_t)i0 * 8), 16, 0, 0); \
    __builtin_amdgcn_global_load_lds( \
        (const __attribute__((address_space(1))) void*)(A + aro1 + _k0), \
        (__attribute__((address_space(3))) void*)(As + _bf * 4096 + (size_t)i1 * 8), 16, 0, 0); }

#define ISSUE_B(kt, breg) { const int _k0 = (kt) * 32 + w * 8; \
    _Pragma("unroll") \
    for (int j = 0; j < 8; ++j) \
        breg[j] = *reinterpret_cast<const float2*>(xb + (long)(_k0 + j) * 4096); }

#define WRITE_B(breg, _bf) { \
    bf16x8 pk0, pk1; \
    _Pragma("unroll") \
    for (int j = 0; j < 8; ++j) { \
        pk0[j] = (short)f2bf(breg[j].x); pk1[j] = (short)f2bf(breg[j].y); } \
    int s0 = w ^ (lane & 7), s1 = (4 + w) ^ (lane & 7); \
    *reinterpret_cast<bf16x8*>(Bs + (_bf) * 4096 + lane * 64 + s0 * 8) = pk0; \
    *reinterpret_cast<bf16x8*>(Bs + (_bf) * 4096 + lane * 64 + s1 * 8) = pk1; }

    float2 bregA[8], bregB[8];
    // prologue: tiles 0,1 in flight (A via gload_lds, B via regs)
    ISSUE_A(0); ISSUE_B(0, bregA);
    ISSUE_A(1); ISSUE_B(1, bregB);
    WRITE_B(bregA, 0);                       // compiler inserts counted vmcnt before pack
    asm volatile("s_waitcnt vmcnt(10) lgkmcnt(0)\n\ts_barrier" ::: "memory");
    __builtin_amdgcn_sched_barrier(0);

    f32x4 acc[4][4];
    #pragma unroll
    for (int i = 0; i < 4; ++i)
        #pragma unroll
        for (int j = 0; j < 4; ++j) acc[i][j] = (f32x4){0.f, 0.f, 0.f, 0.f};

    #pragma unroll
    for (int kt = 0; kt < 12; ++kt) {
        const unsigned short* Ab = As + (kt % 3) * 4096;
        const unsigned short* Bl = Bs + (kt % 3) * 4096;

        bf16x8 av[4], bv[4];
        #pragma unroll
        for (int mf = 0; mf < 4; ++mf) {
            int r = wr * 64 + mf * 16 + li;
            int p = r >> 1;
            int slot = (((r & 1) * 4 + g) ^ (p & 7));
            av[mf] = *reinterpret_cast<const bf16x8*>(Ab + p * 64 + slot * 8);
        }
        #pragma unroll
        for (int nf = 0; nf < 4; ++nf) {
            int r = wc * 64 + nf * 16 + li;
            int p = r >> 1;
            int slot = (((r & 1) * 4 + g) ^ (p & 7));
            bv[nf] = *reinterpret_cast<const bf16x8*>(Bl + p * 64 + slot * 8);
        }
        if (kt < 10) {
            ISSUE_A(kt + 2);
            if (kt & 1) { ISSUE_B(kt + 2, bregB) }
            else        { ISSUE_B(kt + 2, bregA) }
        }
        __builtin_amdgcn_s_setprio(1);
        #pragma unroll
        for (int mf = 0; mf < 4; ++mf)
            #pragma unroll
            for (int nf = 0; nf < 4; ++nf)
                acc[mf][nf] = __builtin_amdgcn_mfma_f32_16x16x32_bf16(av[mf], bv[nf], acc[mf][nf], 0, 0, 0);
        __builtin_amdgcn_s_setprio(0);
        if (kt < 11) {
            // write tile kt+1's B (regs arrived; compiler waits on use). A(kt+1) was
            // issued BEFORE B(kt+1) -> its gload_lds retired by the same implicit vmcnt.
            if (kt & 1) { WRITE_B(bregA, (kt + 1) % 3) }
            else        { WRITE_B(bregB, (kt + 1) % 3) }
            asm volatile("s_waitcnt lgkmcnt(0)\n\ts_barrier" ::: "memory");
            __builtin_amdgcn_sched_barrier(0);
        }
    }
#undef ISSUE_A
#undef ISSUE_B
#undef WRITE_B

    __syncthreads();   // hot-loop LDS reads done; As/Bs now reusable

    // LDS reuse: Ksh [32][128] = As[0..4095], Vsh [64][128] = As[4096..12287]
    unsigned short* Ksh = As;
    unsigned short* Vsh = As + 4096;
    float* psl = reinterpret_cast<float*>(Bs);   // [2][32]

    if (wr == 0) {
        // ---- q rows (mf 0,1): packed us4 to qT
        #pragma unroll
        for (int mf = 0; mf < 2; ++mf) {
            int ml = mf * 16 + g * 4;                  // 0..31
            #pragma unroll
            for (int nf = 0; nf < 4; ++nf) {
                int n = n0 + wc * 64 + nf * 16 + li;
                f32x4 v = acc[mf][nf];
                us4 o = { f2bf(v.x + bias[m0 + ml]),     f2bf(v.y + bias[m0 + ml + 1]),
                          f2bf(v.z + bias[m0 + ml + 2]), f2bf(v.w + bias[m0 + ml + 3]) };
                *reinterpret_cast<us4*>(q_out + (((long)b * 4096 + n) << 8) + head * 32 + ml) = o;
            }
        }
        // ---- k rows (mf 2,3): exp into Ksh + row sums
        float rs[2][4] = {{0.f,0.f,0.f,0.f},{0.f,0.f,0.f,0.f}};
        #pragma unroll
        for (int mm = 0; mm < 2; ++mm) {
            #pragma unroll
            for (int nf = 0; nf < 4; ++nf) {
                int nl = wc * 64 + nf * 16 + li;
                f32x4 v = acc[mm + 2][nf];
                #pragma unroll
                for (int r = 0; r < 4; ++r) {
                    int kd = mm * 16 + g * 4 + r;
                    float e = __expf(v[r] + bias[m0 + 32 + kd]);
                    rs[mm][r] += e;
                    Ksh[kd * 128 + ((((nl >> 3) ^ (kd & 7)) << 3) | (nl & 7))] = f2bf(e);
                }
            }
        }
        #pragma unroll
        for (int mm = 0; mm < 2; ++mm)
            #pragma unroll
            for (int r = 0; r < 4; ++r) {
                float s = rs[mm][r];
                s += __shfl_xor(s, 1); s += __shfl_xor(s, 2);
                s += __shfl_xor(s, 4); s += __shfl_xor(s, 8);
                if (li == 0) psl[wc * 32 + mm * 16 + g * 4 + r] = s;
            }
    } else {
        // ---- v rows (all mf): bias, bf16 into Vsh
        #pragma unroll
        for (int mf = 0; mf < 4; ++mf) {
            #pragma unroll
            for (int nf = 0; nf < 4; ++nf) {
                int nl = wc * 64 + nf * 16 + li;
                f32x4 v = acc[mf][nf];
                #pragma unroll
                for (int r = 0; r < 4; ++r) {
                    int d = mf * 16 + g * 4 + r;
                    Vsh[d * 128 + ((((nl >> 3) ^ (d & 7)) << 3) | (nl & 7))] =
                        f2bf(v[r] + bias[m0 + 64 + d]);
                }
            }
        }
    }
    __syncthreads();

    // ---- mini-GEMM: ctx_part[kd 32][d 64] = Ksh @ Vsh^T over n=128; wave w owns d-cols w*16..+16
    f32x4 c2[2] = {(f32x4){0.f,0.f,0.f,0.f}, (f32x4){0.f,0.f,0.f,0.f}};
    #pragma unroll
    for (int ks = 0; ks < 4; ++ks) {
        int rd = w * 16 + li;
        bf16x8 a0 = *reinterpret_cast<const bf16x8*>(Ksh + li * 128        + ((((ks * 4 + g) ^ (li & 7)) << 3)));
        bf16x8 a1 = *reinterpret_cast<const bf16x8*>(Ksh + (16 + li) * 128 + ((((ks * 4 + g) ^ ((16 + li) & 7)) << 3)));
        bf16x8 bb = *reinterpret_cast<const bf16x8*>(Vsh + rd * 128        + ((((ks * 4 + g) ^ (rd & 7)) << 3)));
        c2[0] = __builtin_amdgcn_mfma_f32_16x16x32_bf16(a0, bb, c2[0], 0, 0, 0);
        c2[1] = __builtin_amdgcn_mfma_f32_16x16x32_bf16(a1, bb, c2[1], 0, 0, 0);
    }
    const int bh = b * 8 + head;
    const long pbase = ((long)chunk * 64 + bh) * 2048;
    #pragma unroll
    for (int mm = 0; mm < 2; ++mm)
        #pragma unroll
        for (int r = 0; r < 4; ++r)
            part[pbase + (mm * 16 + g * 4 + r) * 64 + w * 16 + li] = c2[mm][r];
    if (tid < 32)
        psums[((long)chunk * 64 + bh) * 32 + tid] = psl[tid] + psl[32 + tid];
}

// ---------------- reduce 32 chunks, normalize -> ctxT[bh][d][kd] bf16 ----------------
__global__ __launch_bounds__(256) void ctx_reduce_k(const float* __restrict__ part,
                                                    const float* __restrict__ psums,
                                                    unsigned short* __restrict__ ctxT)
{
    int t = blockIdx.x * 256 + threadIdx.x;   // < 131072
    int bh = t >> 11, i = t & 2047;
    int kd = i & 31, d = i >> 5;
    float s = 0.f, den = 0.f;
    #pragma unroll
    for (int c = 0; c < 32; ++c) {
        s   += part[((long)c * 64 + bh) * 2048 + kd * 64 + d];
        den += psums[((long)c * 64 + bh) * 32 + kd];
    }
    ctxT[t] = f2bf(s / den);
}

// ---------------- fused proj: tall-M block (M=384), softmax+attend once, GEMM ----------------
__global__ __launch_bounds__(512, 2) void proj_fused_k(
    const unsigned short* __restrict__ Wpf,   // [384][512] bf16, k = h*64+d
    const unsigned short* __restrict__ qT,    // [b][4096][256] bf16 (raw q, pre-softmax)
    const unsigned short* __restrict__ ctxT,  // [b*8+h][64 d][32 kd] bf16
    const float* __restrict__ bp,
    float* __restrict__ out)                  // [b][384][4096] f32
{
    __shared__ unsigned short Bsh[128 * 64];
    __shared__ unsigned short As[2][384 * 64];
    const int tid = threadIdx.x, lane = tid & 63, w = tid >> 6;
    const int li = lane & 15, g = lane >> 4;
    const int b = blockIdx.y, n0 = blockIdx.x * 128;

#define PROJ_STAGE(buf, s) { \
    _Pragma("unroll") \
    for (int j = 0; j < 6; ++j) { \
        int idx = j * 512 + tid; \
        int r = idx >> 3; \
        int ls = ((idx & 7) ^ (r & 7)) * 8; \
        __builtin_amdgcn_global_load_lds( \
            (const __attribute__((address_space(1))) void*)(Wpf + (long)r * 512 + (s) * 64 + ls), \
            (__attribute__((address_space(3))) void*)(As[buf] + (size_t)idx * 8), 16, 0, 0); \
    } }

    PROJ_STAGE(0, 0);

    f32x4 acc[3][8];
    #pragma unroll
    for (int i = 0; i < 3; ++i)
        #pragma unroll
        for (int j = 0; j < 8; ++j) acc[i][j] = (f32x4){0.f, 0.f, 0.f, 0.f};

    for (int s = 0; s < 8; ++s) {
        const unsigned short* cb = ctxT + ((long)b * 8 + s) * 2048;
        bf16x8 ca[4], pb;
        #pragma unroll
        for (int df = 0; df < 4; ++df)
            ca[df] = *reinterpret_cast<const bf16x8*>(cb + (df * 16 + li) * 32 + g * 8);
        {
            int n = n0 + w * 16 + li;
            bf16x8 r = *reinterpret_cast<const bf16x8*>(
                qT + (((long)b * 4096 + n) << 8) + s * 32 + g * 8);
            float f[8];
            float mx = -1e30f;
            #pragma unroll
            for (int j = 0; j < 8; ++j) { f[j] = bf2f((unsigned short)r[j]); mx = fmaxf(mx, f[j]); }
            mx = fmaxf(mx, __shfl_xor(mx, 16));
            mx = fmaxf(mx, __shfl_xor(mx, 32));
            float sm = 0.f;
            #pragma unroll
            for (int j = 0; j < 8; ++j) { f[j] = __expf(f[j] - mx); sm += f[j]; }
            sm += __shfl_xor(sm, 16);
            sm += __shfl_xor(sm, 32);
            float inv = 1.f / sm;
            #pragma unroll
            for (int j = 0; j < 8; ++j) pb[j] = (short)f2bf(f[j] * inv);
        }
        us4 bw[4];
        #pragma unroll
        for (int df = 0; df < 4; ++df) {
            f32x4 d = (f32x4){0.f, 0.f, 0.f, 0.f};
            d = __builtin_amdgcn_mfma_f32_16x16x32_bf16(ca[df], pb, d, 0, 0, 0);
            bw[df] = (us4){ f2bf(fmaxf(d.x, 0.f)), f2bf(fmaxf(d.y, 0.f)),
                            f2bf(fmaxf(d.z, 0.f)), f2bf(fmaxf(d.w, 0.f)) };
        }

        __syncthreads();

        if (s < 7) PROJ_STAGE((s + 1) & 1, s + 1);

        #pragma unroll
        for (int df = 0; df < 4; ++df) {
            int n = w * 16 + li;
            int slot = (df * 2 + (g >> 1)) ^ (n & 7);
            *reinterpret_cast<us4*>(Bsh + n * 64 + slot * 8 + (g & 1) * 4) = bw[df];
        }

        asm volatile("s_waitcnt lgkmcnt(0)\n\ts_barrier" ::: "memory");
        __builtin_amdgcn_sched_barrier(0);

        const unsigned short* Ab = As[s & 1];
        #pragma unroll
        for (int kk = 0; kk < 2; ++kk) {
            bf16x8 av[3], bv[8];
            #pragma unroll
            for (int mf = 0; mf < 3; ++mf) {
                int row = w * 48 + mf * 16 + li;
                int ps = ((kk * 4 + g) ^ (row & 7)) * 8;
                av[mf] = *reinterpret_cast<const bf16x8*>(Ab + row * 64 + ps);
            }
            #pragma unroll
            for (int nf = 0; nf < 8; ++nf) {
                int nn = nf * 16 + li;
                int ps = ((kk * 4 + g) ^ (nn & 7)) * 8;
                bv[nf] = *reinterpret_cast<const bf16x8*>(Bsh + nn * 64 + ps);
            }
            #pragma unroll
            for (int mf = 0; mf < 3; ++mf)
                #pragma unroll
                for (int nf = 0; nf < 8; ++nf)
                    acc[mf][nf] = __builtin_amdgcn_mfma_f32_16x16x32_bf16(av[mf], bv[nf], acc[mf][nf], 0, 0, 0);
        }
    }
#undef PROJ_STAGE

    #pragma unroll
    for (int mf = 0; mf < 3; ++mf) {
        int m = w * 48 + mf * 16 + g * 4;
        #pragma unroll
        for (int nf = 0; nf < 8; ++nf) {
            int n = n0 + nf * 16 + li;
            f32x4 v = acc[mf][nf];
            #pragma unroll
            for (int r = 0; r < 4; ++r)
                out[((long)b * 384 + m + r) * 4096 + n] = v[r] + bp[m + r];
        }
    }
}

// ---------------- launch ----------------
extern "C" void kernel_launch(void* const* d_in, const int* in_sizes, int n_in,
                              void* d_out, int out_size, void* d_ws, size_t ws_size,
                              hipStream_t stream) {
    (void)in_sizes; (void)n_in; (void)out_size; (void)ws_size;
    const float* x  = (const float*)d_in[0];
    const float* Wq = (const float*)d_in[1];
    const float* sq = (const float*)d_in[2];
    const float* bq = (const float*)d_in[3];
    const float* Wk = (const float*)d_in[4];
    const float* sk = (const float*)d_in[5];
    const float* bk = (const float*)d_in[6];
    const float* Wv = (const float*)d_in[7];
    const float* sv = (const float*)d_in[8];
    const float* bv = (const float*)d_in[9];
    const float* Wp = (const float*)d_in[10];
    const float* sp = (const float*)d_in[11];
    const float* bp = (const float*)d_in[12];
    float* out = (float*)d_out;

    char* wsb = (char*)d_ws;
    unsigned short* Wqkv  = (unsigned short*)(wsb);              // 786432 B
    unsigned short* Wpf   = (unsigned short*)(wsb + 786432);     // 393216 B
    float*          bqkv  = (float*)(wsb + 1179648);             // 4096 B
    unsigned short* ctxT  = (unsigned short*)(wsb + 1183744);    // 262144 B
    float*          part  = (float*)(wsb + 1445888);             // 16777216 B
    float*          psums = (float*)(wsb + 18223104);            // 262144 B
    unsigned short* qT    = (unsigned short*)(wsb + 18485248);   // 16777216 B -> 35.3 MB total

    fold_weights_k<<<2308, 256, 0, stream>>>(Wq, sq, bq, Wk, sk, bk, Wv, sv, bv, Wp, sp,
                                             Wqkv, Wpf, bqkv);
    gemm_qkv_k<<<dim3(32, 8, 8), 256, 0, stream>>>(Wqkv, x, bqkv, qT, part, psums);
    ctx_reduce_k<<<512, 256, 0, stream>>>(part, psums, ctxT);
    proj_fused_k<<<dim3(32, 8), 512, 0, stream>>>(Wpf, qT, ctxT, bp, out);
}